// Round 1
// baseline (62.682 us; speedup 1.0000x reference)
//
#include <hip/hip_runtime.h>

#define BB 128
#define SS 512
#define HH 1024
#define CHUNKS 8
#define SCHUNK (SS / CHUNKS)   // 64

// d_ws layout:
//   [0, 2048)        : int4 meta[BB]  {t_begin, t_end, l_begin, l_end}
//   [4096, 4096+1MB) : float sums[BB][2][HH]

// ---------------------------------------------------------------------------
// Kernel 1: per-batch SEP scan + mask_len. One 512-thread block per batch.
// ---------------------------------------------------------------------------
__global__ void seg_scan_kernel(const int* __restrict__ input_ids,
                                const int* __restrict__ attn_mask,
                                const int* __restrict__ sep_tok,
                                int4* __restrict__ meta) {
    __shared__ unsigned long long ballots[SS / 64];  // 8 waves
    __shared__ int mask_sum;
    const int b = blockIdx.x;
    const int s = threadIdx.x;

    if (s == 0) mask_sum = 0;
    __syncthreads();

    const int sep = sep_tok[0];
    const int tok = input_ids[b * SS + s];
    const int am  = attn_mask[b * SS + s];

    unsigned long long bal = __ballot(tok == sep);
    if ((s & 63) == 0) ballots[s >> 6] = bal;

    // block sum of attention_mask (tiny kernel; shared atomic is fine)
    if (am) atomicAdd(&mask_sum, am);
    __syncthreads();

    if (s == 0) {
        int cnt = 0, p1 = 0, p2 = 0, p3 = 0;
        for (int w = 0; w < SS / 64; ++w) {
            unsigned long long word = ballots[w];
            while (word) {
                int bit = __builtin_ctzll(word);
                int pos = w * 64 + bit;
                ++cnt;
                if (cnt == 1) p1 = pos;
                else if (cnt == 2) p2 = pos;
                else if (cnt == 3) p3 = pos;
                word &= word - 1;
            }
        }
        int4 m;
        if (cnt >= 2) {
            m.x = 1;                          // title begin (idx >= 1)
            m.y = p1;                         // title end (exclusive)
            if (m.y < m.x) m.y = m.x;         // clamp empty
            m.z = p2 + 1;                     // lead begin
            m.w = (cnt >= 3) ? p3 : mask_sum; // lead end (exclusive)
            if (m.w < m.z) m.w = m.z;         // clamp empty
        } else {
            m.x = 0; m.y = 0; m.z = 0; m.w = 0;  // invalid -> both empty
        }
        meta[b] = m;
    }
}

// ---------------------------------------------------------------------------
// Kernel 2: masked sums. grid = (CHUNKS, B), 256 threads, float4 per thread.
// Accumulate this block's s-chunk intersection with both spans, atomicAdd
// into sums[b][0][:] (title) and sums[b][1][:] (lead).
// ---------------------------------------------------------------------------
__global__ void seg_sum_kernel(const float* __restrict__ hs,
                               const int4* __restrict__ meta,
                               float* __restrict__ sums) {
    const int b    = blockIdx.y;
    const int cbeg = blockIdx.x * SCHUNK;
    const int cend = cbeg + SCHUNK;

    const int4 m = meta[b];
    const int t0 = max(m.x, cbeg), t1 = min(m.y, cend);
    const int l0 = max(m.z, cbeg), l1 = min(m.w, cend);
    if (t0 >= t1 && l0 >= l1) return;

    const int h4 = threadIdx.x;  // owns floats [h4*4, h4*4+4)
    const float4* base = (const float4*)(hs + (size_t)b * SS * HH);

    float4 at = {0.f, 0.f, 0.f, 0.f};
    for (int s = t0; s < t1; ++s) {
        float4 v = base[(size_t)s * (HH / 4) + h4];
        at.x += v.x; at.y += v.y; at.z += v.z; at.w += v.w;
    }
    float4 al = {0.f, 0.f, 0.f, 0.f};
    for (int s = l0; s < l1; ++s) {
        float4 v = base[(size_t)s * (HH / 4) + h4];
        al.x += v.x; al.y += v.y; al.z += v.z; al.w += v.w;
    }

    float* st = sums + ((size_t)b * 2 + 0) * HH + h4 * 4;
    float* sl = sums + ((size_t)b * 2 + 1) * HH + h4 * 4;
    if (t1 > t0) {
        atomicAdd(st + 0, at.x); atomicAdd(st + 1, at.y);
        atomicAdd(st + 2, at.z); atomicAdd(st + 3, at.w);
    }
    if (l1 > l0) {
        atomicAdd(sl + 0, al.x); atomicAdd(sl + 1, al.y);
        atomicAdd(sl + 2, al.z); atomicAdd(sl + 3, al.w);
    }
}

// ---------------------------------------------------------------------------
// Kernel 3: finalize — divide by count or substitute CLS row.
// ---------------------------------------------------------------------------
__global__ void seg_final_kernel(const float* __restrict__ hs,
                                 const int4* __restrict__ meta,
                                 const float* __restrict__ sums,
                                 float* __restrict__ out) {
    const int b  = blockIdx.x;
    const int h4 = threadIdx.x;
    const int4 m = meta[b];
    int tc = m.y - m.x; if (tc < 0) tc = 0;
    int lc = m.w - m.z; if (lc < 0) lc = 0;

    float4 cls = ((const float4*)(hs + (size_t)b * SS * HH))[h4];
    float4 st  = ((const float4*)(sums + (size_t)b * 2 * HH))[h4];
    float4 sl  = ((const float4*)(sums + (size_t)b * 2 * HH + HH))[h4];

    float4 o0, o1;
    if (tc > 0) {
        float c = (float)tc;
        o0.x = st.x / c; o0.y = st.y / c; o0.z = st.z / c; o0.w = st.w / c;
    } else o0 = cls;
    if (lc > 0) {
        float c = (float)lc;
        o1.x = sl.x / c; o1.y = sl.y / c; o1.z = sl.z / c; o1.w = sl.w / c;
    } else o1 = cls;

    ((float4*)out)[(size_t)b * (HH / 4) + h4] = o0;
    ((float4*)(out + (size_t)BB * HH))[(size_t)b * (HH / 4) + h4] = o1;
}

// ---------------------------------------------------------------------------
extern "C" void kernel_launch(void* const* d_in, const int* in_sizes, int n_in,
                              void* d_out, int out_size, void* d_ws, size_t ws_size,
                              hipStream_t stream) {
    const float* hs  = (const float*)d_in[0];
    const int*   ids = (const int*)d_in[1];
    const int*   am  = (const int*)d_in[2];
    const int*   sep = (const int*)d_in[3];
    float* out = (float*)d_out;

    int4*  meta = (int4*)d_ws;
    float* sums = (float*)((char*)d_ws + 4096);

    hipMemsetAsync(sums, 0, (size_t)BB * 2 * HH * sizeof(float), stream);
    seg_scan_kernel<<<BB, SS, 0, stream>>>(ids, am, sep, meta);
    seg_sum_kernel<<<dim3(CHUNKS, BB), 256, 0, stream>>>(hs, meta, sums);
    seg_final_kernel<<<BB, 256, 0, stream>>>(hs, meta, sums, out);
}

// Round 2
// 47.179 us; speedup vs baseline: 1.3286x; 1.3286x over previous
//
#include <hip/hip_runtime.h>

#define BB 128
#define SS 512
#define HH 1024
#define CHUNKS 16
#define SCHUNK (SS / CHUNKS)   // 32

// ---------------------------------------------------------------------------
// Shared meta computation: each block (256 threads) recomputes, for batch b,
// the span descriptor int4 {t_begin, t_end, l_begin, l_end} from input_ids.
// Exactly-3-SEP data makes the thread-0 scan ~10 instructions; the
// attention_mask read only happens in the (never-taken here) cnt<3 branch.
// ---------------------------------------------------------------------------
__device__ __forceinline__ int4 compute_meta(const int* __restrict__ ids,
                                             const int* __restrict__ attn,
                                             int b, int sep) {
    __shared__ unsigned long long words[SS / 64];
    __shared__ int sh_p[4];      // p1, p2, p3, cnt
    __shared__ int sh_mask;
    const int t = threadIdx.x;   // 0..255
    const int* row = ids + b * SS;
    const int tok0 = row[t];
    const int tok1 = row[t + 256];
    const unsigned long long b0 = __ballot(tok0 == sep);
    const unsigned long long b1 = __ballot(tok1 == sep);
    if ((t & 63) == 0) {
        words[t >> 6] = b0;          // s in [64w, 64w+64)
        words[4 + (t >> 6)] = b1;    // s in [256+64w, ...)
    }
    if (t == 0) sh_mask = 0;
    __syncthreads();
    if (t == 0) {
        int cnt = 0, p1 = 0, p2 = 0, p3 = 0;
        for (int i = 0; i < SS / 64; ++i) {
            unsigned long long word = words[i];
            while (word && cnt < 3) {
                const int pos = i * 64 + __builtin_ctzll(word);
                ++cnt;
                if (cnt == 1) p1 = pos;
                else if (cnt == 2) p2 = pos;
                else p3 = pos;
                word &= word - 1;
            }
        }
        sh_p[0] = p1; sh_p[1] = p2; sh_p[2] = p3; sh_p[3] = cnt;
    }
    __syncthreads();
    const int cnt = sh_p[3];
    if (cnt < 3) {   // block-uniform rare branch: need mask_len fallback
        const int* arow = attn + b * SS;
        atomicAdd(&sh_mask, arow[t] + arow[t + 256]);
        __syncthreads();
    }
    int4 m;
    if (cnt >= 2) {
        m.x = 1;
        m.y = max(sh_p[0], 1);           // title [1, p1)
        m.z = sh_p[1] + 1;               // lead begin
        const int e = (cnt >= 3) ? sh_p[2] : sh_mask;
        m.w = max(e, m.z);               // lead end (clamped)
    } else {
        m.x = 0; m.y = 0; m.z = 0; m.w = 0;
    }
    return m;
}

__device__ __forceinline__ void acc4(float4& a, const float4 v) {
    a.x += v.x; a.y += v.y; a.z += v.z; a.w += v.w;
}

// ---------------------------------------------------------------------------
// Path A kernel 1: partial sums, no atomics. grid = (CHUNKS, BB), 256 thr.
// Writes partials[b][chunk][2][HH] ONLY for non-empty intersections; the
// finalize kernel recomputes the same meta so it reads exactly those slots.
// ---------------------------------------------------------------------------
__global__ void seg_sum_partial(const float* __restrict__ hs,
                                const int* __restrict__ ids,
                                const int* __restrict__ attn,
                                const int* __restrict__ sep_tok,
                                float* __restrict__ partials) {
    const int c = blockIdx.x;
    const int b = blockIdx.y;
    const int4 m = compute_meta(ids, attn, b, sep_tok[0]);

    const int cbeg = c * SCHUNK, cend = cbeg + SCHUNK;
    const int t0 = max(m.x, cbeg), t1 = min(m.y, cend);
    const int l0 = max(m.z, cbeg), l1 = min(m.w, cend);
    const bool ht = t1 > t0, hl = l1 > l0;
    if (!ht && !hl) return;

    const int h4 = threadIdx.x;
    const float4* base = (const float4*)(hs + (size_t)b * SS * HH);
    float4* pbase = (float4*)(partials + (size_t)(b * CHUNKS + c) * 2 * HH);

    if (ht) {
        float4 a = {0.f, 0.f, 0.f, 0.f};
        #pragma unroll 4
        for (int s = t0; s < t1; ++s) acc4(a, base[(size_t)s * (HH / 4) + h4]);
        pbase[h4] = a;
    }
    if (hl) {
        float4 a = {0.f, 0.f, 0.f, 0.f};
        #pragma unroll 4
        for (int s = l0; s < l1; ++s) acc4(a, base[(size_t)s * (HH / 4) + h4]);
        pbase[HH / 4 + h4] = a;
    }
}

// ---------------------------------------------------------------------------
// Path A kernel 2: gather partials + divide / CLS fallback.
// grid = (2 spans, BB), 256 thr.
// ---------------------------------------------------------------------------
__global__ void seg_final_partial(const float* __restrict__ hs,
                                  const int* __restrict__ ids,
                                  const int* __restrict__ attn,
                                  const int* __restrict__ sep_tok,
                                  const float* __restrict__ partials,
                                  float* __restrict__ out) {
    const int span = blockIdx.x;   // 0 = title, 1 = lead
    const int b = blockIdx.y;
    const int4 m = compute_meta(ids, attn, b, sep_tok[0]);
    const int h4 = threadIdx.x;

    const int s0 = span == 0 ? m.x : m.z;
    const int s1 = span == 0 ? m.y : m.w;

    float4 a = {0.f, 0.f, 0.f, 0.f};
    #pragma unroll
    for (int c = 0; c < CHUNKS; ++c) {
        const int cbeg = c * SCHUNK, cend = cbeg + SCHUNK;
        const int x0 = max(s0, cbeg), x1 = min(s1, cend);
        if (x1 > x0) {
            const float4* p = (const float4*)(partials +
                (size_t)(b * CHUNKS + c) * 2 * HH + (size_t)span * HH);
            acc4(a, p[h4]);
        }
    }

    const int cntr = max(s1 - s0, 0);
    float4 o;
    if (cntr > 0) {
        const float c = (float)cntr;
        o.x = a.x / c; o.y = a.y / c; o.z = a.z / c; o.w = a.w / c;
    } else {
        o = ((const float4*)(hs + (size_t)b * SS * HH))[h4];  // CLS row
    }
    ((float4*)out)[(size_t)(span * BB + b) * (HH / 4) + h4] = o;
}

// ---------------------------------------------------------------------------
// Path B (fallback if ws too small): atomic accumulation into sums[b][2][HH].
// ---------------------------------------------------------------------------
__global__ void seg_sum_atomic(const float* __restrict__ hs,
                               const int* __restrict__ ids,
                               const int* __restrict__ attn,
                               const int* __restrict__ sep_tok,
                               float* __restrict__ sums) {
    const int c = blockIdx.x;
    const int b = blockIdx.y;
    const int4 m = compute_meta(ids, attn, b, sep_tok[0]);

    const int cbeg = c * SCHUNK, cend = cbeg + SCHUNK;
    const int t0 = max(m.x, cbeg), t1 = min(m.y, cend);
    const int l0 = max(m.z, cbeg), l1 = min(m.w, cend);
    if (t0 >= t1 && l0 >= l1) return;

    const int h4 = threadIdx.x;
    const float4* base = (const float4*)(hs + (size_t)b * SS * HH);
    float* sbase = sums + (size_t)b * 2 * HH;

    if (t1 > t0) {
        float4 a = {0.f, 0.f, 0.f, 0.f};
        #pragma unroll 4
        for (int s = t0; s < t1; ++s) acc4(a, base[(size_t)s * (HH / 4) + h4]);
        atomicAdd(sbase + h4 * 4 + 0, a.x); atomicAdd(sbase + h4 * 4 + 1, a.y);
        atomicAdd(sbase + h4 * 4 + 2, a.z); atomicAdd(sbase + h4 * 4 + 3, a.w);
    }
    if (l1 > l0) {
        float4 a = {0.f, 0.f, 0.f, 0.f};
        #pragma unroll 4
        for (int s = l0; s < l1; ++s) acc4(a, base[(size_t)s * (HH / 4) + h4]);
        float* sl = sbase + HH;
        atomicAdd(sl + h4 * 4 + 0, a.x); atomicAdd(sl + h4 * 4 + 1, a.y);
        atomicAdd(sl + h4 * 4 + 2, a.z); atomicAdd(sl + h4 * 4 + 3, a.w);
    }
}

__global__ void seg_final_atomic(const float* __restrict__ hs,
                                 const int* __restrict__ ids,
                                 const int* __restrict__ attn,
                                 const int* __restrict__ sep_tok,
                                 const float* __restrict__ sums,
                                 float* __restrict__ out) {
    const int span = blockIdx.x;
    const int b = blockIdx.y;
    const int4 m = compute_meta(ids, attn, b, sep_tok[0]);
    const int h4 = threadIdx.x;

    const int s0 = span == 0 ? m.x : m.z;
    const int s1 = span == 0 ? m.y : m.w;
    const int cntr = max(s1 - s0, 0);

    float4 o;
    if (cntr > 0) {
        const float4 a = ((const float4*)(sums + (size_t)b * 2 * HH + (size_t)span * HH))[h4];
        const float c = (float)cntr;
        o.x = a.x / c; o.y = a.y / c; o.z = a.z / c; o.w = a.w / c;
    } else {
        o = ((const float4*)(hs + (size_t)b * SS * HH))[h4];
    }
    ((float4*)out)[(size_t)(span * BB + b) * (HH / 4) + h4] = o;
}

// ---------------------------------------------------------------------------
extern "C" void kernel_launch(void* const* d_in, const int* in_sizes, int n_in,
                              void* d_out, int out_size, void* d_ws, size_t ws_size,
                              hipStream_t stream) {
    const float* hs  = (const float*)d_in[0];
    const int*   ids = (const int*)d_in[1];
    const int*   am  = (const int*)d_in[2];
    const int*   sep = (const int*)d_in[3];
    float* out = (float*)d_out;

    const size_t partial_bytes = (size_t)BB * CHUNKS * 2 * HH * sizeof(float); // 16 MB

    if (ws_size >= partial_bytes) {
        float* partials = (float*)d_ws;
        seg_sum_partial<<<dim3(CHUNKS, BB), 256, 0, stream>>>(hs, ids, am, sep, partials);
        seg_final_partial<<<dim3(2, BB), 256, 0, stream>>>(hs, ids, am, sep, partials, out);
    } else {
        float* sums = (float*)d_ws;   // 1 MB
        hipMemsetAsync(sums, 0, (size_t)BB * 2 * HH * sizeof(float), stream);
        seg_sum_atomic<<<dim3(CHUNKS, BB), 256, 0, stream>>>(hs, ids, am, sep, sums);
        seg_final_atomic<<<dim3(2, BB), 256, 0, stream>>>(hs, ids, am, sep, sums, out);
    }
}